// Round 20
// baseline (395.941 us; speedup 1.0000x reference)
//
#include <hip/hip_runtime.h>
#include <hip/hip_bf16.h>
#include <cstdint>

#define DIM   768
#define HEADS 12
#define HD    64
#define NTOK  197
#define BATCH 64
#define MROWS (BATCH*NTOK)   /* 12608 */
#define MPAD  12672          /* 99*128 */
#define HIDN  3072
#define QSCALE 0.125f
#define LNEPS 1e-6f

typedef __bf16 bf16;
typedef __bf16 bf16x8 __attribute__((ext_vector_type(8)));
typedef __bf16 bf16x4 __attribute__((ext_vector_type(4)));
typedef float  f32x4  __attribute__((ext_vector_type(4)));

__device__ inline void gload_lds16(const void* src, void* dst) {
  __builtin_amdgcn_global_load_lds(
      (__attribute__((address_space(1))) void*)(src),
      (__attribute__((address_space(3))) void*)(dst), 16, 0, 0);
}

// ---------------- weight f32 -> bf16 convert (all 4 weights, one launch) ------
__global__ __launch_bounds__(256) void conv4_kernel(
    const float* __restrict__ s0, bf16* __restrict__ d0, int n0,
    const float* __restrict__ s1, bf16* __restrict__ d1, int n1,
    const float* __restrict__ s2, bf16* __restrict__ d2, int n2,
    const float* __restrict__ s3, bf16* __restrict__ d3, int n3) {
  int i = blockIdx.x * 256 + threadIdx.x;
  const float* s; bf16* d; int k;
  if (i < n0) { s = s0; d = d0; k = i; }
  else if (i < n0 + n1) { s = s1; d = d1; k = i - n0; }
  else if (i < n0 + n1 + n2) { s = s2; d = d2; k = i - n0 - n1; }
  else if (i < n0 + n1 + n2 + n3) { s = s3; d = d3; k = i - n0 - n1 - n2; }
  else return;
  float4 f = ((const float4*)s)[k];
  bf16x4 o; o.x = (bf16)f.x; o.y = (bf16)f.y; o.z = (bf16)f.z; o.w = (bf16)f.w;
  ((bf16x4*)d)[k] = o;
}

// ---------------- relative position bias precompute ----------------
__global__ __launch_bounds__(256) void bias_kernel(const float* __restrict__ rh,
                                                   const float* __restrict__ rw,
                                                   const int* __restrict__ hidx,
                                                   const int* __restrict__ widx,
                                                   float* __restrict__ bias) {
  int idx = blockIdx.x * 256 + threadIdx.x;
  const int NN = NTOK * NTOK;
  if (idx >= HEADS * NN) return;
  int h  = idx / NN;
  int ij = idx - h * NN;
  bias[idx] = rh[hidx[ij] * HEADS + h] + rw[widx[ij] * HEADS + h];
}

// ---------------- LayerNorm f32 -> bf16 ----------------
__global__ __launch_bounds__(256) void ln_kernel(const float* __restrict__ x,
                                                 const float* __restrict__ w,
                                                 const float* __restrict__ b,
                                                 bf16* __restrict__ out) {
  int row = blockIdx.x;
  int tid = threadIdx.x;
  const float* xr = x + (size_t)row * DIM;
  float v0 = xr[tid], v1 = xr[tid + 256], v2 = xr[tid + 512];
  float s  = v0 + v1 + v2;
  float s2 = v0 * v0 + v1 * v1 + v2 * v2;
#pragma unroll
  for (int d = 1; d < 64; d <<= 1) { s += __shfl_xor(s, d); s2 += __shfl_xor(s2, d); }
  __shared__ float red[8];
  int wv = tid >> 6, ln = tid & 63;
  if (ln == 0) { red[wv] = s; red[wv + 4] = s2; }
  __syncthreads();
  s  = red[0] + red[1] + red[2] + red[3];
  s2 = red[4] + red[5] + red[6] + red[7];
  float mean = s * (1.0f / DIM);
  float var  = s2 * (1.0f / DIM) - mean * mean;
  float rs   = rsqrtf(var + LNEPS);
  bf16* outr = out + (size_t)row * DIM;
  outr[tid]       = (bf16)((v0 - mean) * rs * w[tid]       + b[tid]);
  outr[tid + 256] = (bf16)((v1 - mean) * rs * w[tid + 256] + b[tid + 256]);
  outr[tid + 512] = (bf16)((v2 - mean) * rs * w[tid + 512] + b[tid + 512]);
}

// ---- 128xBN BK=64 swizzled GEMM, XCD-chunked, serial stage->sync->compute ----
// BN=128: 4 waves in 2x2, each 64x64 (acc[4][4]). LDS 32KB, minw=4 -> 4 blk/CU.
// BN=64 : 4 waves stacked in M, each 32x64 (acc[2][4]). LDS 24KB, minw=6.
// EPI 0: qkv scatter; 1: residual f32; 2: gelu bf16.
template <int EPI, int BN>
__global__ __launch_bounds__(256, (BN == 128) ? 4 : 6)
void gemm128(const bf16* __restrict__ A, const bf16* __restrict__ Bw,
             int K, int Ncols, int Ntiles,
             const float* __restrict__ p0, const float* __restrict__ p1,
             void* __restrict__ outp) {
  constexpr int MF = (BN == 128) ? 4 : 2;   // M fragments per wave
  constexpr int BR = BN / 32;               // B staging rounds
  __shared__ __align__(16) bf16 As[128 * 64];   // 16KB
  __shared__ __align__(16) bf16 Bs[BN * 64];    // 16KB or 8KB
  const int tid  = threadIdx.x;
  const int wave = tid >> 6, lane = tid & 63;
  const int lr16 = lane & 15, hi16 = lane >> 4;

  // bijective XCD chunking (m204)
  const int nwg = gridDim.x;
  const int q8 = nwg >> 3, r8 = nwg & 7;
  const int xcd = blockIdx.x & 7, jj8 = blockIdx.x >> 3;
  const int chunk = (xcd < r8 ? xcd * (q8 + 1) : r8 * (q8 + 1) + (xcd - r8) * q8) + jj8;
  const int mt = chunk / Ntiles, nt = chunk - mt * Ntiles;
  const int rowBase = mt * 128;
  const int colBase = nt * BN;
  const size_t Kb = (size_t)K * 2;
  const int KT = K >> 6;

  // swizzle: LDS[row][unit u] = G[row][u ^ (row&7)]; read unit g -> u = g ^ (row&7)
  const int s7 = lr16 & 7;
  const int colk0 = (hi16 ^ s7) * 16;          // kk=0 (k 0..31)
  const int colk1 = ((4 + hi16) ^ s7) * 16;    // kk=1 (k 32..63)
  const int wmoff = (BN == 128) ? (wave >> 1) * 64 : wave * 32;
  const int wnoff = (BN == 128) ? (wave & 1) * 64 : 0;
  const int rowb_a = (wmoff + lr16) * 128;     // + m*2048
  const int rowb_b = (wnoff + lr16) * 128;     // + n*2048

  // staging: round r covers rows r*32 + wave*8 + (lane>>3); lane unit = lane&7
  const int srow = wave * 8 + (lane >> 3);
  const int scb  = (((lane & 7) ^ ((lane >> 3) & 7)) * 16);
  const char* aSrcP[4];
  const char* bSrcP[BR];
#pragma unroll
  for (int r = 0; r < 4; ++r) {
    int ra = rowBase + r * 32 + srow;
    if (ra > MROWS - 1) ra = MROWS - 1;        // clamp A rows (tail tile)
    aSrcP[r] = (const char*)A + (size_t)ra * Kb + scb;
  }
#pragma unroll
  for (int r = 0; r < BR; ++r)
    bSrcP[r] = (const char*)Bw + (size_t)(colBase + r * 32 + srow) * Kb + scb;

  f32x4 acc[MF][4] = {};

  for (int t = 0; t < KT; ++t) {
    const size_t koff = (size_t)t * 128;
#pragma unroll
    for (int r = 0; r < 4; ++r)
      gload_lds16(aSrcP[r] + koff, (char*)As + (r * 32 + wave * 8) * 128);
#pragma unroll
    for (int r = 0; r < BR; ++r)
      gload_lds16(bSrcP[r] + koff, (char*)Bs + (r * 32 + wave * 8) * 128);
    __syncthreads();   // drains vmcnt -> staged tile visible

    bf16x8 bfr[4][2];
#pragma unroll
    for (int n = 0; n < 4; ++n) {
      bfr[n][0] = *(const bf16x8*)((const char*)Bs + rowb_b + n * 2048 + colk0);
      bfr[n][1] = *(const bf16x8*)((const char*)Bs + rowb_b + n * 2048 + colk1);
    }
#pragma unroll
    for (int m = 0; m < MF; ++m) {
      bf16x8 a0 = *(const bf16x8*)((const char*)As + rowb_a + m * 2048 + colk0);
      bf16x8 a1 = *(const bf16x8*)((const char*)As + rowb_a + m * 2048 + colk1);
#pragma unroll
      for (int n = 0; n < 4; ++n) {
        acc[m][n] = __builtin_amdgcn_mfma_f32_16x16x32_bf16(a0, bfr[n][0], acc[m][n], 0, 0, 0);
        acc[m][n] = __builtin_amdgcn_mfma_f32_16x16x32_bf16(a1, bfr[n][1], acc[m][n], 0, 0, 0);
      }
    }
    __syncthreads();   // all reads done before next stage
  }

  // ---- epilogue (C/D layout: col=lane&15, row=(lane>>4)*4+reg)
  const int rl = hi16 * 4;
  const int cl = lr16;
#pragma unroll
  for (int m = 0; m < MF; ++m) {
#pragma unroll
    for (int n = 0; n < 4; ++n) {
#pragma unroll
      for (int r = 0; r < 4; ++r) {
        int row = rowBase + wmoff + m * 16 + rl + r;
        int col = colBase + wnoff + n * 16 + cl;
        if (row >= MROWS) continue;
        float v = acc[m][n][r];
        if constexpr (EPI == 0) {
          int which = col / DIM;
          int jj = col - which * DIM;
          if (which == 0) v = (v + p0[jj]) * QSCALE;
          else if (which == 2) v = v + p1[jj];
          int bb = row / NTOK, nt2 = row - bb * NTOK;
          int h = jj >> 6, hd = jj & 63;
          ((bf16*)outp)[((size_t)(which * 768 + bb * HEADS + h) * NTOK + nt2) * 64 + hd] = (bf16)v;
        } else if constexpr (EPI == 1) {
          ((float*)outp)[(size_t)row * Ncols + col] =
              p1[(size_t)row * Ncols + col] + v + p0[col];
        } else {
          float t2 = v + p0[col];
          float g = 0.5f * t2 * (1.0f + erff(t2 * 0.70710678118654752f));
          ((bf16*)outp)[(size_t)row * Ncols + col] = (bf16)g;
        }
      }
    }
  }
}

// ---- fused attention v7: q-split (2 blocks per (b,h)), no-max exp softmax ----
// (round-18 proven version: dbuf P chunks, Ob fits the 2560B per-wave region)
#define VTS 232   /* Vt row stride (elements) */
__global__ __launch_bounds__(512, 4)
void attn_kernel(const bf16* __restrict__ qkv, const float* __restrict__ bias,
                 bf16* __restrict__ out) {
  const int bh = blockIdx.x >> 1;
  const int half = blockIdx.x & 1;
  const int b = bh / HEADS, h = bh - b * HEADS;
  const bf16* qg = qkv + (size_t)bh * NTOK * HD;
  const bf16* kg = qg + (size_t)768 * NTOK * HD;
  const bf16* vg = qg + (size_t)1536 * NTOK * HD;

  __shared__ __align__(16) bf16 Vt[64 * VTS];       // 29.0KB
  __shared__ __align__(16) bf16 Ps[8][2][16 * 40];  // 20.0KB dbuf P chunks

  const int tid = threadIdx.x;
  for (int i = tid; i < NTOK * HD; i += 512) {
    int j = i >> 6, d = i & 63;
    Vt[d * VTS + j] = vg[i];
  }
  for (int i = tid; i < 64 * (VTS - NTOK); i += 512) {
    int d = i / (VTS - NTOK), j = NTOK + (i - d * (VTS - NTOK));
    Vt[d * VTS + j] = (bf16)0.0f;
  }
  __syncthreads();

  const int wave = tid >> 6, lane = tid & 63;
  const int lr = lane & 15, lg = lane >> 4;
  const float* bh_bias = bias + (size_t)h * NTOK * NTOK;
  const int mi = 2 * wave + half;     // even tiles in half 0, odd in half 1

  if (mi <= 12) {
    int qrow = mi * 16 + lr; if (qrow > NTOK - 1) qrow = NTOK - 1;
    bf16x8 aq0 = *(const bf16x8*)(qg + (size_t)qrow * 64 + lg * 8);
    bf16x8 aq1 = *(const bf16x8*)(qg + (size_t)qrow * 64 + 32 + lg * 8);

    f32x4 oacc[4] = {};
    float l0 = 0.f, l1 = 0.f, l2 = 0.f, l3 = 0.f;
    const int ivb = (mi * 16 + lg * 4 < NTOK) ? mi * 16 + lg * 4 : NTOK - 1;
    const int iv0 = (ivb + 0 > NTOK - 1) ? NTOK - 1 : ivb + 0;
    const int iv1 = (ivb + 1 > NTOK - 1) ? NTOK - 1 : ivb + 1;
    const int iv2 = (ivb + 2 > NTOK - 1) ? NTOK - 1 : ivb + 2;
    const int iv3 = (ivb + 3 > NTOK - 1) ? NTOK - 1 : ivb + 3;

    const bf16* kbase = kg + (size_t)lr * 64 + lg * 8;
    bf16x8 ka0 = *(const bf16x8*)(kbase);
    bf16x8 ka1 = *(const bf16x8*)(kbase + 32);
    bf16x8 kb0 = *(const bf16x8*)(kbase + 16 * 64);
    bf16x8 kb1 = *(const bf16x8*)(kbase + 16 * 64 + 32);

#pragma unroll 1
    for (int kt = 0; kt < 7; ++kt) {
      const int ktn = (kt < 6) ? kt + 1 : 6;
      const bf16* knext = kg + (size_t)(ktn * 32 + lr) * 64 + lg * 8;
      bf16x8 na0 = *(const bf16x8*)(knext);
      bf16x8 na1 = *(const bf16x8*)(knext + 32);
      bf16x8 nb0 = *(const bf16x8*)(knext + 16 * 64);
      bf16x8 nb1 = *(const bf16x8*)(knext + 16 * 64 + 32);

      f32x4 s0 = {}, s1 = {};
      s0 = __builtin_amdgcn_mfma_f32_16x16x32_bf16(aq0, ka0, s0, 0, 0, 0);
      s0 = __builtin_amdgcn_mfma_f32_16x16x32_bf16(aq1, ka1, s0, 0, 0, 0);
      s1 = __builtin_amdgcn_mfma_f32_16x16x32_bf16(aq0, kb0, s1, 0, 0, 0);
      s1 = __builtin_amdgcn_mfma_f32_16x16x32_bf16(aq1, kb1, s1, 0, 0, 0);

      const int j0 = kt * 32 + lr;
      const int jc0 = (j0 > NTOK - 1) ? NTOK - 1 : j0;
      const int jc1 = (j0 + 16 > NTOK - 1) ? NTOK - 1 : j0 + 16;
      const bool v0 = (j0 < NTOK), v1 = (j0 + 16 < NTOK);

      bf16* buf = &Ps[wave][kt & 1][0];
      {
        float e0 = v0 ? __expf(s0[0] + bh_bias[(size_t)iv0 * NTOK + jc0]) : 0.f;
        float e1 = v1 ? __expf(s1[0] + bh_bias[(size_t)iv0 * NTOK + jc1]) : 0.f;
        l0 += e0 + e1;
        buf[(lg * 4 + 0) * 40 + lr]      = (bf16)e0;
        buf[(lg * 4 + 0) * 40 + 16 + lr] = (bf16)e1;
      }
      {
        float e0 = v0 ? __expf(s0[1] + bh_bias[(size_t)iv1 * NTOK + jc0]) : 0.f;
        float e1 = v1 ? __expf(s1[1] + bh_bias[(size_t)iv1 * NTOK + jc1]) : 0.f;
        l1 += e0 + e1;
        buf[(lg * 4 + 1) * 40 + lr]      = (bf16)e0;
        buf[(lg * 4 + 1) * 40 + 16 + lr] = (bf16)e1;
      }
      {
        float e0 = v0 ? __expf(s0[2] + bh_bias[(size_t)iv2 * NTOK + jc0]) : 0.f;
        float e1 = v1 ? __expf(s1[2] + bh_bias[(size_t)iv2 * NTOK + jc1]) : 0.f;
        l2 += e0 + e1;
        buf[(lg * 4 + 2) * 40 + lr]      = (bf16)e0;
        buf[(lg * 4 + 2) * 40 + 16 + lr] = (bf16)e1;
      }
      {
        float e0 = v0 ? __expf(s0[3] + bh_bias[(size_t)iv3 * NTOK + jc0]) : 0.f;
        float e1 = v1 ? __expf(s1[3] + bh_bias[(size_t)iv3 * NTOK + jc1]) : 0.f;
        l3 += e0 + e1;
        buf[(lg * 4 + 3) * 40 + lr]      = (bf16)e0;
        buf[(lg * 4 + 3) * 40 + 16 + lr] = (bf16)e1;
      }
      asm volatile("s_waitcnt lgkmcnt(0)" ::: "memory");
      __builtin_amdgcn_sched_barrier(0);
      bf16x8 pa = *(const bf16x8*)&buf[lr * 40 + lg * 8];
#pragma unroll
      for (int nd = 0; nd < 4; ++nd) {
        bf16x8 bv = *(const bf16x8*)&Vt[(nd * 16 + lr) * VTS + kt * 32 + lg * 8];
        oacc[nd] = __builtin_amdgcn_mfma_f32_16x16x32_bf16(pa, bv, oacc[nd], 0, 0, 0);
      }
      ka0 = na0; ka1 = na1; kb0 = nb0; kb1 = nb1;
    }

    float rowinv[4];
    {
      float ls[4] = {l0, l1, l2, l3};
#pragma unroll
      for (int r = 0; r < 4; ++r) {
        float v = ls[r];
#pragma unroll
        for (int d = 1; d < 16; d <<= 1) v += __shfl_xor(v, d);
        rowinv[r] = 1.0f / v;
      }
    }

    bf16* Ob = &Ps[wave][0][0];   // 16*72*2 = 2304B <= 2560B wave region
#pragma unroll
    for (int nd = 0; nd < 4; ++nd)
#pragma unroll
      for (int r = 0; r < 4; ++r)
        Ob[(lg * 4 + r) * 72 + nd * 16 + lr] = (bf16)(oacc[nd][r] * rowinv[r]);
    asm volatile("s_waitcnt lgkmcnt(0)" ::: "memory");
    __builtin_amdgcn_sched_barrier(0);
    const int rows = NTOK - mi * 16;
#pragma unroll
    for (int pass = 0; pass < 2; ++pass) {
      int orow = pass * 8 + (lane >> 3);
      if (orow < rows) {
        bf16x8 v = *(const bf16x8*)&Ob[orow * 72 + (lane & 7) * 8];
        *(bf16x8*)(out + (size_t)(b * NTOK + mi * 16 + orow) * DIM + h * 64 + (lane & 7) * 8) = v;
      }
    }
  }
}

// ---------------- launch ----------------
extern "C" void kernel_launch(void* const* d_in, const int* in_sizes, int n_in,
                              void* d_out, int out_size, void* d_ws, size_t ws_size,
                              hipStream_t stream) {
  const float* x    = (const float*)d_in[0];
  const float* n1w  = (const float*)d_in[1];
  const float* n1b  = (const float*)d_in[2];
  const float* qkvw = (const float*)d_in[3];
  const float* qb   = (const float*)d_in[4];
  const float* vb   = (const float*)d_in[5];
  const float* pw   = (const float*)d_in[6];
  const float* pb   = (const float*)d_in[7];
  const float* rh   = (const float*)d_in[8];
  const float* rw   = (const float*)d_in[9];
  const float* n2w  = (const float*)d_in[10];
  const float* n2b  = (const float*)d_in[11];
  const float* f1w  = (const float*)d_in[12];
  const float* f1b  = (const float*)d_in[13];
  const float* f2w  = (const float*)d_in[14];
  const float* f2b  = (const float*)d_in[15];
  const int* hidx   = (const int*)d_in[16];
  const int* widx   = (const int*)d_in[17];

  char* ws = (char*)d_ws;
  size_t off = 0;
  auto alloc = [&](size_t bytes) {
    void* p = ws + off;
    off += (bytes + 255) & ~(size_t)255;
    return p;
  };
  bf16* wqkv  = (bf16*)alloc((size_t)2304 * 768 * 2);
  bf16* wproj = (bf16*)alloc((size_t)768 * 768 * 2);
  bf16* wfc1  = (bf16*)alloc((size_t)3072 * 768 * 2);
  bf16* wfc2  = (bf16*)alloc((size_t)768 * 3072 * 2);
  float* biasT = (float*)alloc((size_t)HEADS * NTOK * NTOK * 4);
  bf16* hbf = (bf16*)alloc((size_t)MROWS * 768 * 2);
  float* x1 = (float*)alloc((size_t)MROWS * 768 * 4);
  char* region = (char*)alloc((size_t)MPAD * HIDN * 2);
  bf16* qkv   = (bf16*)region;                                       // 58.1 MB
  bf16* attno = (bf16*)(region + (size_t)2304 * NTOK * 64 * 2);      // 19.4 MB
  bf16* mbuf  = (bf16*)region;                                       // FC1 out overlays qkv+attno

  const int c0 = 2304 * 768 / 4, c1 = 768 * 768 / 4, c2 = 3072 * 768 / 4, c3 = 768 * 3072 / 4;
  conv4_kernel<<<(c0 + c1 + c2 + c3 + 255) / 256, 256, 0, stream>>>(
      qkvw, wqkv, c0, pw, wproj, c1, f1w, wfc1, c2, f2w, wfc2, c3);
  bias_kernel<<<(HEADS * NTOK * NTOK + 255) / 256, 256, 0, stream>>>(rh, rw, hidx, widx, biasT);

  const int MT = MPAD / 128;  // 99
  ln_kernel<<<MROWS, 256, 0, stream>>>(x, n1w, n1b, hbf);
  gemm128<0, 128><<<MT * 18, 256, 0, stream>>>(hbf, wqkv, 768, 2304, 18, qb, vb, qkv);
  attn_kernel<<<1536, 512, 0, stream>>>(qkv, biasT, attno);
  gemm128<1, 64><<<MT * 12, 256, 0, stream>>>(attno, wproj, 768, 768, 12, pb, x, x1);
  ln_kernel<<<MROWS, 256, 0, stream>>>(x1, n2w, n2b, hbf);
  gemm128<2, 128><<<MT * 24, 256, 0, stream>>>(hbf, wfc1, 768, HIDN, 24, f1b, nullptr, mbuf);
  gemm128<1, 64><<<MT * 12, 256, 0, stream>>>(mbuf, wfc2, HIDN, 768, 12, f2b, x1, d_out);
}

// Round 21
// 390.716 us; speedup vs baseline: 1.0134x; 1.0134x over previous
//
#include <hip/hip_runtime.h>
#include <hip/hip_bf16.h>
#include <cstdint>

#define DIM   768
#define HEADS 12
#define HD    64
#define NTOK  197
#define BATCH 64
#define MROWS (BATCH*NTOK)   /* 12608 */
#define MPAD  12672          /* 99*128 */
#define HIDN  3072
#define QSCALE 0.125f
#define LNEPS 1e-6f

typedef __bf16 bf16;
typedef __bf16 bf16x8 __attribute__((ext_vector_type(8)));
typedef __bf16 bf16x4 __attribute__((ext_vector_type(4)));
typedef float  f32x4  __attribute__((ext_vector_type(4)));

__device__ inline void gload_lds16(const void* src, void* dst) {
  __builtin_amdgcn_global_load_lds(
      (__attribute__((address_space(1))) void*)(src),
      (__attribute__((address_space(3))) void*)(dst), 16, 0, 0);
}

// ---------------- weight f32 -> bf16 convert (all 4 weights, one launch) ------
__global__ __launch_bounds__(256) void conv4_kernel(
    const float* __restrict__ s0, bf16* __restrict__ d0, int n0,
    const float* __restrict__ s1, bf16* __restrict__ d1, int n1,
    const float* __restrict__ s2, bf16* __restrict__ d2, int n2,
    const float* __restrict__ s3, bf16* __restrict__ d3, int n3) {
  int i = blockIdx.x * 256 + threadIdx.x;
  const float* s; bf16* d; int k;
  if (i < n0) { s = s0; d = d0; k = i; }
  else if (i < n0 + n1) { s = s1; d = d1; k = i - n0; }
  else if (i < n0 + n1 + n2) { s = s2; d = d2; k = i - n0 - n1; }
  else if (i < n0 + n1 + n2 + n3) { s = s3; d = d3; k = i - n0 - n1 - n2; }
  else return;
  float4 f = ((const float4*)s)[k];
  bf16x4 o; o.x = (bf16)f.x; o.y = (bf16)f.y; o.z = (bf16)f.z; o.w = (bf16)f.w;
  ((bf16x4*)d)[k] = o;
}

// ---------------- relative position bias precompute ----------------
__global__ __launch_bounds__(256) void bias_kernel(const float* __restrict__ rh,
                                                   const float* __restrict__ rw,
                                                   const int* __restrict__ hidx,
                                                   const int* __restrict__ widx,
                                                   float* __restrict__ bias) {
  int idx = blockIdx.x * 256 + threadIdx.x;
  const int NN = NTOK * NTOK;
  if (idx >= HEADS * NN) return;
  int h  = idx / NN;
  int ij = idx - h * NN;
  bias[idx] = rh[hidx[ij] * HEADS + h] + rw[widx[ij] * HEADS + h];
}

// ---------------- LayerNorm (f32 or bf16 input) -> bf16 ----------------
template <typename TIN>
__global__ __launch_bounds__(256) void ln_kernel(const TIN* __restrict__ x,
                                                 const float* __restrict__ w,
                                                 const float* __restrict__ b,
                                                 bf16* __restrict__ out) {
  int row = blockIdx.x;
  int tid = threadIdx.x;
  const TIN* xr = x + (size_t)row * DIM;
  float v0 = (float)xr[tid], v1 = (float)xr[tid + 256], v2 = (float)xr[tid + 512];
  float s  = v0 + v1 + v2;
  float s2 = v0 * v0 + v1 * v1 + v2 * v2;
#pragma unroll
  for (int d = 1; d < 64; d <<= 1) { s += __shfl_xor(s, d); s2 += __shfl_xor(s2, d); }
  __shared__ float red[8];
  int wv = tid >> 6, ln = tid & 63;
  if (ln == 0) { red[wv] = s; red[wv + 4] = s2; }
  __syncthreads();
  s  = red[0] + red[1] + red[2] + red[3];
  s2 = red[4] + red[5] + red[6] + red[7];
  float mean = s * (1.0f / DIM);
  float var  = s2 * (1.0f / DIM) - mean * mean;
  float rs   = rsqrtf(var + LNEPS);
  bf16* outr = out + (size_t)row * DIM;
  outr[tid]       = (bf16)((v0 - mean) * rs * w[tid]       + b[tid]);
  outr[tid + 256] = (bf16)((v1 - mean) * rs * w[tid + 256] + b[tid + 256]);
  outr[tid + 512] = (bf16)((v2 - mean) * rs * w[tid + 512] + b[tid + 512]);
}

// ---- 128xBN BK=64 swizzled GEMM, XCD-chunked, serial stage->sync->compute ----
// BN=128: 4 waves in 2x2, each 64x64 (acc[4][4]). LDS 32KB, minw=4.
// BN=64 : 4 waves stacked in M, each 32x64 (acc[2][4]). LDS 24KB, minw=6.
// EPI 0: qkv scatter; 1: residual f32->f32; 2: gelu bf16;
// EPI 3: residual f32-in -> bf16 out; EPI 4: residual bf16-in -> f32 out.
template <int EPI, int BN>
__global__ __launch_bounds__(256, (BN == 128) ? 4 : 6)
void gemm128(const bf16* __restrict__ A, const bf16* __restrict__ Bw,
             int K, int Ncols, int Ntiles,
             const float* __restrict__ p0, const float* __restrict__ p1,
             void* __restrict__ outp) {
  constexpr int MF = (BN == 128) ? 4 : 2;   // M fragments per wave
  constexpr int BR = BN / 32;               // B staging rounds
  __shared__ __align__(16) bf16 As[128 * 64];   // 16KB
  __shared__ __align__(16) bf16 Bs[BN * 64];    // 16KB or 8KB
  const int tid  = threadIdx.x;
  const int wave = tid >> 6, lane = tid & 63;
  const int lr16 = lane & 15, hi16 = lane >> 4;

  // bijective XCD chunking (m204)
  const int nwg = gridDim.x;
  const int q8 = nwg >> 3, r8 = nwg & 7;
  const int xcd = blockIdx.x & 7, jj8 = blockIdx.x >> 3;
  const int chunk = (xcd < r8 ? xcd * (q8 + 1) : r8 * (q8 + 1) + (xcd - r8) * q8) + jj8;
  const int mt = chunk / Ntiles, nt = chunk - mt * Ntiles;
  const int rowBase = mt * 128;
  const int colBase = nt * BN;
  const size_t Kb = (size_t)K * 2;
  const int KT = K >> 6;

  // swizzle: LDS[row][unit u] = G[row][u ^ (row&7)]; read unit g -> u = g ^ (row&7)
  const int s7 = lr16 & 7;
  const int colk0 = (hi16 ^ s7) * 16;          // kk=0 (k 0..31)
  const int colk1 = ((4 + hi16) ^ s7) * 16;    // kk=1 (k 32..63)
  const int wmoff = (BN == 128) ? (wave >> 1) * 64 : wave * 32;
  const int wnoff = (BN == 128) ? (wave & 1) * 64 : 0;
  const int rowb_a = (wmoff + lr16) * 128;     // + m*2048
  const int rowb_b = (wnoff + lr16) * 128;     // + n*2048

  // staging: round r covers rows r*32 + wave*8 + (lane>>3); lane unit = lane&7
  const int srow = wave * 8 + (lane >> 3);
  const int scb  = (((lane & 7) ^ ((lane >> 3) & 7)) * 16);
  const char* aSrcP[4];
  const char* bSrcP[BR];
#pragma unroll
  for (int r = 0; r < 4; ++r) {
    int ra = rowBase + r * 32 + srow;
    if (ra > MROWS - 1) ra = MROWS - 1;        // clamp A rows (tail tile)
    aSrcP[r] = (const char*)A + (size_t)ra * Kb + scb;
  }
#pragma unroll
  for (int r = 0; r < BR; ++r)
    bSrcP[r] = (const char*)Bw + (size_t)(colBase + r * 32 + srow) * Kb + scb;

  f32x4 acc[MF][4] = {};

  for (int t = 0; t < KT; ++t) {
    const size_t koff = (size_t)t * 128;
#pragma unroll
    for (int r = 0; r < 4; ++r)
      gload_lds16(aSrcP[r] + koff, (char*)As + (r * 32 + wave * 8) * 128);
#pragma unroll
    for (int r = 0; r < BR; ++r)
      gload_lds16(bSrcP[r] + koff, (char*)Bs + (r * 32 + wave * 8) * 128);
    __syncthreads();   // drains vmcnt -> staged tile visible

    bf16x8 bfr[4][2];
#pragma unroll
    for (int n = 0; n < 4; ++n) {
      bfr[n][0] = *(const bf16x8*)((const char*)Bs + rowb_b + n * 2048 + colk0);
      bfr[n][1] = *(const bf16x8*)((const char*)Bs + rowb_b + n * 2048 + colk1);
    }
#pragma unroll
    for (int m = 0; m < MF; ++m) {
      bf16x8 a0 = *(const bf16x8*)((const char*)As + rowb_a + m * 2048 + colk0);
      bf16x8 a1 = *(const bf16x8*)((const char*)As + rowb_a + m * 2048 + colk1);
#pragma unroll
      for (int n = 0; n < 4; ++n) {
        acc[m][n] = __builtin_amdgcn_mfma_f32_16x16x32_bf16(a0, bfr[n][0], acc[m][n], 0, 0, 0);
        acc[m][n] = __builtin_amdgcn_mfma_f32_16x16x32_bf16(a1, bfr[n][1], acc[m][n], 0, 0, 0);
      }
    }
    __syncthreads();   // all reads done before next stage
  }

  // ---- epilogue (C/D layout: col=lane&15, row=(lane>>4)*4+reg)
  const int rl = hi16 * 4;
  const int cl = lr16;
#pragma unroll
  for (int m = 0; m < MF; ++m) {
#pragma unroll
    for (int n = 0; n < 4; ++n) {
#pragma unroll
      for (int r = 0; r < 4; ++r) {
        int row = rowBase + wmoff + m * 16 + rl + r;
        int col = colBase + wnoff + n * 16 + cl;
        if (row >= MROWS) continue;
        float v = acc[m][n][r];
        if constexpr (EPI == 0) {
          int which = col / DIM;
          int jj = col - which * DIM;
          if (which == 0) v = (v + p0[jj]) * QSCALE;
          else if (which == 2) v = v + p1[jj];
          int bb = row / NTOK, nt2 = row - bb * NTOK;
          int h = jj >> 6, hd = jj & 63;
          ((bf16*)outp)[((size_t)(which * 768 + bb * HEADS + h) * NTOK + nt2) * 64 + hd] = (bf16)v;
        } else if constexpr (EPI == 1) {
          ((float*)outp)[(size_t)row * Ncols + col] =
              p1[(size_t)row * Ncols + col] + v + p0[col];
        } else if constexpr (EPI == 2) {
          float t2 = v + p0[col];
          float g = 0.5f * t2 * (1.0f + erff(t2 * 0.70710678118654752f));
          ((bf16*)outp)[(size_t)row * Ncols + col] = (bf16)g;
        } else if constexpr (EPI == 3) {
          ((bf16*)outp)[(size_t)row * Ncols + col] =
              (bf16)(p1[(size_t)row * Ncols + col] + v + p0[col]);
        } else {  // EPI == 4: bf16 residual in, f32 out
          const bf16* p1b = (const bf16*)(const void*)p1;
          ((float*)outp)[(size_t)row * Ncols + col] =
              (float)p1b[(size_t)row * Ncols + col] + v + p0[col];
        }
      }
    }
  }
}

// ---- fused attention v7: q-split (2 blocks per (b,h)), no-max exp softmax ----
#define VTS 232   /* Vt row stride (elements) */
__global__ __launch_bounds__(512, 4)
void attn_kernel(const bf16* __restrict__ qkv, const float* __restrict__ bias,
                 bf16* __restrict__ out) {
  const int bh = blockIdx.x >> 1;
  const int half = blockIdx.x & 1;
  const int b = bh / HEADS, h = bh - b * HEADS;
  const bf16* qg = qkv + (size_t)bh * NTOK * HD;
  const bf16* kg = qg + (size_t)768 * NTOK * HD;
  const bf16* vg = qg + (size_t)1536 * NTOK * HD;

  __shared__ __align__(16) bf16 Vt[64 * VTS];       // 29.0KB
  __shared__ __align__(16) bf16 Ps[8][2][16 * 40];  // 20.0KB dbuf P chunks

  const int tid = threadIdx.x;
  for (int i = tid; i < NTOK * HD; i += 512) {
    int j = i >> 6, d = i & 63;
    Vt[d * VTS + j] = vg[i];
  }
  for (int i = tid; i < 64 * (VTS - NTOK); i += 512) {
    int d = i / (VTS - NTOK), j = NTOK + (i - d * (VTS - NTOK));
    Vt[d * VTS + j] = (bf16)0.0f;
  }
  __syncthreads();

  const int wave = tid >> 6, lane = tid & 63;
  const int lr = lane & 15, lg = lane >> 4;
  const float* bh_bias = bias + (size_t)h * NTOK * NTOK;
  const int mi = 2 * wave + half;     // even tiles in half 0, odd in half 1

  if (mi <= 12) {
    int qrow = mi * 16 + lr; if (qrow > NTOK - 1) qrow = NTOK - 1;
    bf16x8 aq0 = *(const bf16x8*)(qg + (size_t)qrow * 64 + lg * 8);
    bf16x8 aq1 = *(const bf16x8*)(qg + (size_t)qrow * 64 + 32 + lg * 8);

    f32x4 oacc[4] = {};
    float l0 = 0.f, l1 = 0.f, l2 = 0.f, l3 = 0.f;
    const int ivb = (mi * 16 + lg * 4 < NTOK) ? mi * 16 + lg * 4 : NTOK - 1;
    const int iv0 = (ivb + 0 > NTOK - 1) ? NTOK - 1 : ivb + 0;
    const int iv1 = (ivb + 1 > NTOK - 1) ? NTOK - 1 : ivb + 1;
    const int iv2 = (ivb + 2 > NTOK - 1) ? NTOK - 1 : ivb + 2;
    const int iv3 = (ivb + 3 > NTOK - 1) ? NTOK - 1 : ivb + 3;

    const bf16* kbase = kg + (size_t)lr * 64 + lg * 8;
    bf16x8 ka0 = *(const bf16x8*)(kbase);
    bf16x8 ka1 = *(const bf16x8*)(kbase + 32);
    bf16x8 kb0 = *(const bf16x8*)(kbase + 16 * 64);
    bf16x8 kb1 = *(const bf16x8*)(kbase + 16 * 64 + 32);

#pragma unroll 1
    for (int kt = 0; kt < 7; ++kt) {
      const int ktn = (kt < 6) ? kt + 1 : 6;
      const bf16* knext = kg + (size_t)(ktn * 32 + lr) * 64 + lg * 8;
      bf16x8 na0 = *(const bf16x8*)(knext);
      bf16x8 na1 = *(const bf16x8*)(knext + 32);
      bf16x8 nb0 = *(const bf16x8*)(knext + 16 * 64);
      bf16x8 nb1 = *(const bf16x8*)(knext + 16 * 64 + 32);

      f32x4 s0 = {}, s1 = {};
      s0 = __builtin_amdgcn_mfma_f32_16x16x32_bf16(aq0, ka0, s0, 0, 0, 0);
      s0 = __builtin_amdgcn_mfma_f32_16x16x32_bf16(aq1, ka1, s0, 0, 0, 0);
      s1 = __builtin_amdgcn_mfma_f32_16x16x32_bf16(aq0, kb0, s1, 0, 0, 0);
      s1 = __builtin_amdgcn_mfma_f32_16x16x32_bf16(aq1, kb1, s1, 0, 0, 0);

      const int j0 = kt * 32 + lr;
      const int jc0 = (j0 > NTOK - 1) ? NTOK - 1 : j0;
      const int jc1 = (j0 + 16 > NTOK - 1) ? NTOK - 1 : j0 + 16;
      const bool v0 = (j0 < NTOK), v1 = (j0 + 16 < NTOK);

      bf16* buf = &Ps[wave][kt & 1][0];
      {
        float e0 = v0 ? __expf(s0[0] + bh_bias[(size_t)iv0 * NTOK + jc0]) : 0.f;
        float e1 = v1 ? __expf(s1[0] + bh_bias[(size_t)iv0 * NTOK + jc1]) : 0.f;
        l0 += e0 + e1;
        buf[(lg * 4 + 0) * 40 + lr]      = (bf16)e0;
        buf[(lg * 4 + 0) * 40 + 16 + lr] = (bf16)e1;
      }
      {
        float e0 = v0 ? __expf(s0[1] + bh_bias[(size_t)iv1 * NTOK + jc0]) : 0.f;
        float e1 = v1 ? __expf(s1[1] + bh_bias[(size_t)iv1 * NTOK + jc1]) : 0.f;
        l1 += e0 + e1;
        buf[(lg * 4 + 1) * 40 + lr]      = (bf16)e0;
        buf[(lg * 4 + 1) * 40 + 16 + lr] = (bf16)e1;
      }
      {
        float e0 = v0 ? __expf(s0[2] + bh_bias[(size_t)iv2 * NTOK + jc0]) : 0.f;
        float e1 = v1 ? __expf(s1[2] + bh_bias[(size_t)iv2 * NTOK + jc1]) : 0.f;
        l2 += e0 + e1;
        buf[(lg * 4 + 2) * 40 + lr]      = (bf16)e0;
        buf[(lg * 4 + 2) * 40 + 16 + lr] = (bf16)e1;
      }
      {
        float e0 = v0 ? __expf(s0[3] + bh_bias[(size_t)iv3 * NTOK + jc0]) : 0.f;
        float e1 = v1 ? __expf(s1[3] + bh_bias[(size_t)iv3 * NTOK + jc1]) : 0.f;
        l3 += e0 + e1;
        buf[(lg * 4 + 3) * 40 + lr]      = (bf16)e0;
        buf[(lg * 4 + 3) * 40 + 16 + lr] = (bf16)e1;
      }
      asm volatile("s_waitcnt lgkmcnt(0)" ::: "memory");
      __builtin_amdgcn_sched_barrier(0);
      bf16x8 pa = *(const bf16x8*)&buf[lr * 40 + lg * 8];
#pragma unroll
      for (int nd = 0; nd < 4; ++nd) {
        bf16x8 bv = *(const bf16x8*)&Vt[(nd * 16 + lr) * VTS + kt * 32 + lg * 8];
        oacc[nd] = __builtin_amdgcn_mfma_f32_16x16x32_bf16(pa, bv, oacc[nd], 0, 0, 0);
      }
      ka0 = na0; ka1 = na1; kb0 = nb0; kb1 = nb1;
    }

    float rowinv[4];
    {
      float ls[4] = {l0, l1, l2, l3};
#pragma unroll
      for (int r = 0; r < 4; ++r) {
        float v = ls[r];
#pragma unroll
        for (int d = 1; d < 16; d <<= 1) v += __shfl_xor(v, d);
        rowinv[r] = 1.0f / v;
      }
    }

    bf16* Ob = &Ps[wave][0][0];   // 16*72*2 = 2304B <= 2560B wave region
#pragma unroll
    for (int nd = 0; nd < 4; ++nd)
#pragma unroll
      for (int r = 0; r < 4; ++r)
        Ob[(lg * 4 + r) * 72 + nd * 16 + lr] = (bf16)(oacc[nd][r] * rowinv[r]);
    asm volatile("s_waitcnt lgkmcnt(0)" ::: "memory");
    __builtin_amdgcn_sched_barrier(0);
    const int rows = NTOK - mi * 16;
#pragma unroll
    for (int pass = 0; pass < 2; ++pass) {
      int orow = pass * 8 + (lane >> 3);
      if (orow < rows) {
        bf16x8 v = *(const bf16x8*)&Ob[orow * 72 + (lane & 7) * 8];
        *(bf16x8*)(out + (size_t)(b * NTOK + mi * 16 + orow) * DIM + h * 64 + (lane & 7) * 8) = v;
      }
    }
  }
}

// ---------------- launch ----------------
extern "C" void kernel_launch(void* const* d_in, const int* in_sizes, int n_in,
                              void* d_out, int out_size, void* d_ws, size_t ws_size,
                              hipStream_t stream) {
  const float* x    = (const float*)d_in[0];
  const float* n1w  = (const float*)d_in[1];
  const float* n1b  = (const float*)d_in[2];
  const float* qkvw = (const float*)d_in[3];
  const float* qb   = (const float*)d_in[4];
  const float* vb   = (const float*)d_in[5];
  const float* pw   = (const float*)d_in[6];
  const float* pb   = (const float*)d_in[7];
  const float* rh   = (const float*)d_in[8];
  const float* rw   = (const float*)d_in[9];
  const float* n2w  = (const float*)d_in[10];
  const float* n2b  = (const float*)d_in[11];
  const float* f1w  = (const float*)d_in[12];
  const float* f1b  = (const float*)d_in[13];
  const float* f2w  = (const float*)d_in[14];
  const float* f2b  = (const float*)d_in[15];
  const int* hidx   = (const int*)d_in[16];
  const int* widx   = (const int*)d_in[17];

  char* ws = (char*)d_ws;
  size_t off = 0;
  auto alloc = [&](size_t bytes) {
    void* p = ws + off;
    off += (bytes + 255) & ~(size_t)255;
    return p;
  };
  bf16* wqkv  = (bf16*)alloc((size_t)2304 * 768 * 2);
  bf16* wproj = (bf16*)alloc((size_t)768 * 768 * 2);
  bf16* wfc1  = (bf16*)alloc((size_t)3072 * 768 * 2);
  bf16* wfc2  = (bf16*)alloc((size_t)768 * 3072 * 2);
  float* biasT = (float*)alloc((size_t)HEADS * NTOK * NTOK * 4);
  bf16* hbf = (bf16*)alloc((size_t)MROWS * 768 * 2);
  bf16* x1  = (bf16*)alloc((size_t)MROWS * 768 * 2);     // bf16 residual intermediate
  char* region = (char*)alloc((size_t)MPAD * HIDN * 2);
  bf16* qkv   = (bf16*)region;                                       // 58.1 MB
  bf16* attno = (bf16*)(region + (size_t)2304 * NTOK * 64 * 2);      // 19.4 MB
  bf16* mbuf  = (bf16*)region;                                       // FC1 out overlays qkv+attno

  const int c0 = 2304 * 768 / 4, c1 = 768 * 768 / 4, c2 = 3072 * 768 / 4, c3 = 768 * 3072 / 4;
  conv4_kernel<<<(c0 + c1 + c2 + c3 + 255) / 256, 256, 0, stream>>>(
      qkvw, wqkv, c0, pw, wproj, c1, f1w, wfc1, c2, f2w, wfc2, c3);
  bias_kernel<<<(HEADS * NTOK * NTOK + 255) / 256, 256, 0, stream>>>(rh, rw, hidx, widx, biasT);

  const int MT = MPAD / 128;  // 99
  ln_kernel<float><<<MROWS, 256, 0, stream>>>(x, n1w, n1b, hbf);
  gemm128<0, 128><<<MT * 18, 256, 0, stream>>>(hbf, wqkv, 768, 2304, 18, qb, vb, qkv);
  attn_kernel<<<1536, 512, 0, stream>>>(qkv, biasT, attno);
  gemm128<3, 64><<<MT * 12, 256, 0, stream>>>(attno, wproj, 768, 768, 12, pb, x, x1);
  ln_kernel<bf16><<<MROWS, 256, 0, stream>>>(x1, n2w, n2b, hbf);
  gemm128<2, 128><<<MT * 24, 256, 0, stream>>>(hbf, wfc1, 768, HIDN, 24, f1b, nullptr, mbuf);
  gemm128<4, 64><<<MT * 12, 256, 0, stream>>>(mbuf, wfc2, HIDN, 768, 12, f2b,
                                              (const float*)(const void*)x1, d_out);
}

// Round 22
// 378.177 us; speedup vs baseline: 1.0470x; 1.0332x over previous
//
#include <hip/hip_runtime.h>
#include <hip/hip_bf16.h>
#include <cstdint>

#define DIM   768
#define HEADS 12
#define HD    64
#define NTOK  197
#define BATCH 64
#define MROWS (BATCH*NTOK)   /* 12608 */
#define MPAD  12672          /* 99*128 */
#define HIDN  3072
#define QSCALE 0.125f
#define LNEPS 1e-6f

typedef __bf16 bf16;
typedef __bf16 bf16x8 __attribute__((ext_vector_type(8)));
typedef __bf16 bf16x4 __attribute__((ext_vector_type(4)));
typedef float  f32x4  __attribute__((ext_vector_type(4)));

__device__ inline void gload_lds16(const void* src, void* dst) {
  __builtin_amdgcn_global_load_lds(
      (__attribute__((address_space(1))) void*)(src),
      (__attribute__((address_space(3))) void*)(dst), 16, 0, 0);
}

// ---------------- weight f32 -> bf16 convert (all 4 weights, one launch) ------
__global__ __launch_bounds__(256) void conv4_kernel(
    const float* __restrict__ s0, bf16* __restrict__ d0, int n0,
    const float* __restrict__ s1, bf16* __restrict__ d1, int n1,
    const float* __restrict__ s2, bf16* __restrict__ d2, int n2,
    const float* __restrict__ s3, bf16* __restrict__ d3, int n3) {
  int i = blockIdx.x * 256 + threadIdx.x;
  const float* s; bf16* d; int k;
  if (i < n0) { s = s0; d = d0; k = i; }
  else if (i < n0 + n1) { s = s1; d = d1; k = i - n0; }
  else if (i < n0 + n1 + n2) { s = s2; d = d2; k = i - n0 - n1; }
  else if (i < n0 + n1 + n2 + n3) { s = s3; d = d3; k = i - n0 - n1 - n2; }
  else return;
  float4 f = ((const float4*)s)[k];
  bf16x4 o; o.x = (bf16)f.x; o.y = (bf16)f.y; o.z = (bf16)f.z; o.w = (bf16)f.w;
  ((bf16x4*)d)[k] = o;
}

// ---------------- relative position bias precompute ----------------
__global__ __launch_bounds__(256) void bias_kernel(const float* __restrict__ rh,
                                                   const float* __restrict__ rw,
                                                   const int* __restrict__ hidx,
                                                   const int* __restrict__ widx,
                                                   float* __restrict__ bias) {
  int idx = blockIdx.x * 256 + threadIdx.x;
  const int NN = NTOK * NTOK;
  if (idx >= HEADS * NN) return;
  int h  = idx / NN;
  int ij = idx - h * NN;
  bias[idx] = rh[hidx[ij] * HEADS + h] + rw[widx[ij] * HEADS + h];
}

// ---------------- LayerNorm (f32 or bf16 input) -> bf16 ----------------
template <typename TIN>
__global__ __launch_bounds__(256) void ln_kernel(const TIN* __restrict__ x,
                                                 const float* __restrict__ w,
                                                 const float* __restrict__ b,
                                                 bf16* __restrict__ out) {
  int row = blockIdx.x;
  int tid = threadIdx.x;
  const TIN* xr = x + (size_t)row * DIM;
  float v0 = (float)xr[tid], v1 = (float)xr[tid + 256], v2 = (float)xr[tid + 512];
  float s  = v0 + v1 + v2;
  float s2 = v0 * v0 + v1 * v1 + v2 * v2;
#pragma unroll
  for (int d = 1; d < 64; d <<= 1) { s += __shfl_xor(s, d); s2 += __shfl_xor(s2, d); }
  __shared__ float red[8];
  int wv = tid >> 6, ln = tid & 63;
  if (ln == 0) { red[wv] = s; red[wv + 4] = s2; }
  __syncthreads();
  s  = red[0] + red[1] + red[2] + red[3];
  s2 = red[4] + red[5] + red[6] + red[7];
  float mean = s * (1.0f / DIM);
  float var  = s2 * (1.0f / DIM) - mean * mean;
  float rs   = rsqrtf(var + LNEPS);
  bf16* outr = out + (size_t)row * DIM;
  outr[tid]       = (bf16)((v0 - mean) * rs * w[tid]       + b[tid]);
  outr[tid + 256] = (bf16)((v1 - mean) * rs * w[tid + 256] + b[tid + 256]);
  outr[tid + 512] = (bf16)((v2 - mean) * rs * w[tid + 512] + b[tid + 512]);
}

// ---- 128xBN BK=64 swizzled GEMM, XCD-chunked, serial stage->sync->compute ----
// EPI 0: qkv scatter; 1: residual f32->f32; 2: gelu bf16;
// EPI 3: residual f32-in -> bf16 out; EPI 4: residual bf16-in -> f32 out.
template <int EPI, int BN>
__global__ __launch_bounds__(256, (BN == 128) ? 4 : 6)
void gemm128(const bf16* __restrict__ A, const bf16* __restrict__ Bw,
             int K, int Ncols, int Ntiles,
             const float* __restrict__ p0, const float* __restrict__ p1,
             void* __restrict__ outp) {
  constexpr int MF = (BN == 128) ? 4 : 2;   // M fragments per wave
  constexpr int BR = BN / 32;               // B staging rounds
  __shared__ __align__(16) bf16 As[128 * 64];   // 16KB
  __shared__ __align__(16) bf16 Bs[BN * 64];    // 16KB or 8KB
  const int tid  = threadIdx.x;
  const int wave = tid >> 6, lane = tid & 63;
  const int lr16 = lane & 15, hi16 = lane >> 4;

  // bijective XCD chunking (m204)
  const int nwg = gridDim.x;
  const int q8 = nwg >> 3, r8 = nwg & 7;
  const int xcd = blockIdx.x & 7, jj8 = blockIdx.x >> 3;
  const int chunk = (xcd < r8 ? xcd * (q8 + 1) : r8 * (q8 + 1) + (xcd - r8) * q8) + jj8;
  const int mt = chunk / Ntiles, nt = chunk - mt * Ntiles;
  const int rowBase = mt * 128;
  const int colBase = nt * BN;
  const size_t Kb = (size_t)K * 2;
  const int KT = K >> 6;

  // swizzle: LDS[row][unit u] = G[row][u ^ (row&7)]; read unit g -> u = g ^ (row&7)
  const int s7 = lr16 & 7;
  const int colk0 = (hi16 ^ s7) * 16;          // kk=0 (k 0..31)
  const int colk1 = ((4 + hi16) ^ s7) * 16;    // kk=1 (k 32..63)
  const int wmoff = (BN == 128) ? (wave >> 1) * 64 : wave * 32;
  const int wnoff = (BN == 128) ? (wave & 1) * 64 : 0;
  const int rowb_a = (wmoff + lr16) * 128;     // + m*2048
  const int rowb_b = (wnoff + lr16) * 128;     // + n*2048

  // staging: round r covers rows r*32 + wave*8 + (lane>>3); lane unit = lane&7
  const int srow = wave * 8 + (lane >> 3);
  const int scb  = (((lane & 7) ^ ((lane >> 3) & 7)) * 16);
  const char* aSrcP[4];
  const char* bSrcP[BR];
#pragma unroll
  for (int r = 0; r < 4; ++r) {
    int ra = rowBase + r * 32 + srow;
    if (ra > MROWS - 1) ra = MROWS - 1;        // clamp A rows (tail tile)
    aSrcP[r] = (const char*)A + (size_t)ra * Kb + scb;
  }
#pragma unroll
  for (int r = 0; r < BR; ++r)
    bSrcP[r] = (const char*)Bw + (size_t)(colBase + r * 32 + srow) * Kb + scb;

  f32x4 acc[MF][4] = {};

  for (int t = 0; t < KT; ++t) {
    const size_t koff = (size_t)t * 128;
#pragma unroll
    for (int r = 0; r < 4; ++r)
      gload_lds16(aSrcP[r] + koff, (char*)As + (r * 32 + wave * 8) * 128);
#pragma unroll
    for (int r = 0; r < BR; ++r)
      gload_lds16(bSrcP[r] + koff, (char*)Bs + (r * 32 + wave * 8) * 128);
    __syncthreads();   // drains vmcnt -> staged tile visible

    bf16x8 bfr[4][2];
#pragma unroll
    for (int n = 0; n < 4; ++n) {
      bfr[n][0] = *(const bf16x8*)((const char*)Bs + rowb_b + n * 2048 + colk0);
      bfr[n][1] = *(const bf16x8*)((const char*)Bs + rowb_b + n * 2048 + colk1);
    }
#pragma unroll
    for (int m = 0; m < MF; ++m) {
      bf16x8 a0 = *(const bf16x8*)((const char*)As + rowb_a + m * 2048 + colk0);
      bf16x8 a1 = *(const bf16x8*)((const char*)As + rowb_a + m * 2048 + colk1);
#pragma unroll
      for (int n = 0; n < 4; ++n) {
        acc[m][n] = __builtin_amdgcn_mfma_f32_16x16x32_bf16(a0, bfr[n][0], acc[m][n], 0, 0, 0);
        acc[m][n] = __builtin_amdgcn_mfma_f32_16x16x32_bf16(a1, bfr[n][1], acc[m][n], 0, 0, 0);
      }
    }
    __syncthreads();   // all reads done before next stage
  }

  // ---- epilogue (C/D layout: col=lane&15, row=(lane>>4)*4+reg)
  const int rl = hi16 * 4;
  const int cl = lr16;
#pragma unroll
  for (int m = 0; m < MF; ++m) {
#pragma unroll
    for (int n = 0; n < 4; ++n) {
#pragma unroll
      for (int r = 0; r < 4; ++r) {
        int row = rowBase + wmoff + m * 16 + rl + r;
        int col = colBase + wnoff + n * 16 + cl;
        if (row >= MROWS) continue;
        float v = acc[m][n][r];
        if constexpr (EPI == 0) {
          int which = col / DIM;
          int jj = col - which * DIM;
          if (which == 0) v = (v + p0[jj]) * QSCALE;
          else if (which == 2) v = v + p1[jj];
          int bb = row / NTOK, nt2 = row - bb * NTOK;
          int h = jj >> 6, hd = jj & 63;
          ((bf16*)outp)[((size_t)(which * 768 + bb * HEADS + h) * NTOK + nt2) * 64 + hd] = (bf16)v;
        } else if constexpr (EPI == 1) {
          ((float*)outp)[(size_t)row * Ncols + col] =
              p1[(size_t)row * Ncols + col] + v + p0[col];
        } else if constexpr (EPI == 2) {
          float t2 = v + p0[col];
          float g = 0.5f * t2 * (1.0f + erff(t2 * 0.70710678118654752f));
          ((bf16*)outp)[(size_t)row * Ncols + col] = (bf16)g;
        } else if constexpr (EPI == 3) {
          ((bf16*)outp)[(size_t)row * Ncols + col] =
              (bf16)(p1[(size_t)row * Ncols + col] + v + p0[col]);
        } else {  // EPI == 4: bf16 residual in, f32 out
          const bf16* p1b = (const bf16*)(const void*)p1;
          ((float*)outp)[(size_t)row * Ncols + col] =
              (float)p1b[(size_t)row * Ncols + col] + v + p0[col];
        }
      }
    }
  }
}

// ---- fused attention v9: q-split, no-max exp softmax, K + bias prefetch ----
// Bias loads for chunk kt+1 issued (as named scalars, no arrays/branches) right
// after the QK MFMAs; their L2 latency hides under exp+LDS+PV of chunk kt.
#define VTS 232   /* Vt row stride (elements) */
__global__ __launch_bounds__(512, 4)
void attn_kernel(const bf16* __restrict__ qkv, const float* __restrict__ bias,
                 bf16* __restrict__ out) {
  const int bh = blockIdx.x >> 1;
  const int half = blockIdx.x & 1;
  const int b = bh / HEADS, h = bh - b * HEADS;
  const bf16* qg = qkv + (size_t)bh * NTOK * HD;
  const bf16* kg = qg + (size_t)768 * NTOK * HD;
  const bf16* vg = qg + (size_t)1536 * NTOK * HD;

  __shared__ __align__(16) bf16 Vt[64 * VTS];       // 29.0KB
  __shared__ __align__(16) bf16 Ps[8][2][16 * 40];  // 20.0KB dbuf P chunks

  const int tid = threadIdx.x;
  for (int i = tid; i < NTOK * HD; i += 512) {
    int j = i >> 6, d = i & 63;
    Vt[d * VTS + j] = vg[i];
  }
  for (int i = tid; i < 64 * (VTS - NTOK); i += 512) {
    int d = i / (VTS - NTOK), j = NTOK + (i - d * (VTS - NTOK));
    Vt[d * VTS + j] = (bf16)0.0f;
  }
  __syncthreads();

  const int wave = tid >> 6, lane = tid & 63;
  const int lr = lane & 15, lg = lane >> 4;
  const float* bh_bias = bias + (size_t)h * NTOK * NTOK;
  const int mi = 2 * wave + half;     // even tiles in half 0, odd in half 1

  if (mi <= 12) {
    int qrow = mi * 16 + lr; if (qrow > NTOK - 1) qrow = NTOK - 1;
    bf16x8 aq0 = *(const bf16x8*)(qg + (size_t)qrow * 64 + lg * 8);
    bf16x8 aq1 = *(const bf16x8*)(qg + (size_t)qrow * 64 + 32 + lg * 8);

    f32x4 oacc[4] = {};
    float l0 = 0.f, l1 = 0.f, l2 = 0.f, l3 = 0.f;
    const int ivb = (mi * 16 + lg * 4 < NTOK) ? mi * 16 + lg * 4 : NTOK - 1;
    const int iv0 = (ivb + 0 > NTOK - 1) ? NTOK - 1 : ivb + 0;
    const int iv1 = (ivb + 1 > NTOK - 1) ? NTOK - 1 : ivb + 1;
    const int iv2 = (ivb + 2 > NTOK - 1) ? NTOK - 1 : ivb + 2;
    const int iv3 = (ivb + 3 > NTOK - 1) ? NTOK - 1 : ivb + 3;
    const float* br0 = bh_bias + (size_t)iv0 * NTOK;
    const float* br1 = bh_bias + (size_t)iv1 * NTOK;
    const float* br2 = bh_bias + (size_t)iv2 * NTOK;
    const float* br3 = bh_bias + (size_t)iv3 * NTOK;

    const bf16* kbase = kg + (size_t)lr * 64 + lg * 8;
    bf16x8 ka0 = *(const bf16x8*)(kbase);
    bf16x8 ka1 = *(const bf16x8*)(kbase + 32);
    bf16x8 kb0 = *(const bf16x8*)(kbase + 16 * 64);
    bf16x8 kb1 = *(const bf16x8*)(kbase + 16 * 64 + 32);

    // prefetch bias for kt=0 (cols lr and 16+lr, both < 197)
    float cb0 = br0[lr],      cb1 = br1[lr],      cb2 = br2[lr],      cb3 = br3[lr];
    float cb4 = br0[16 + lr], cb5 = br1[16 + lr], cb6 = br2[16 + lr], cb7 = br3[16 + lr];

#pragma unroll 1
    for (int kt = 0; kt < 7; ++kt) {
      const int ktn = (kt < 6) ? kt + 1 : 6;
      const bf16* knext = kg + (size_t)(ktn * 32 + lr) * 64 + lg * 8;
      bf16x8 na0 = *(const bf16x8*)(knext);
      bf16x8 na1 = *(const bf16x8*)(knext + 32);
      bf16x8 nb0 = *(const bf16x8*)(knext + 16 * 64);
      bf16x8 nb1 = *(const bf16x8*)(knext + 16 * 64 + 32);

      f32x4 s0 = {}, s1 = {};
      s0 = __builtin_amdgcn_mfma_f32_16x16x32_bf16(aq0, ka0, s0, 0, 0, 0);
      s0 = __builtin_amdgcn_mfma_f32_16x16x32_bf16(aq1, ka1, s0, 0, 0, 0);
      s1 = __builtin_amdgcn_mfma_f32_16x16x32_bf16(aq0, kb0, s1, 0, 0, 0);
      s1 = __builtin_amdgcn_mfma_f32_16x16x32_bf16(aq1, kb1, s1, 0, 0, 0);

      // prefetch next chunk's bias (clamped; masked lanes discard). Issued here so
      // the L2 latency hides under the exp+LDS+PV below.
      const int jn0 = (ktn * 32 + lr > NTOK - 1) ? NTOK - 1 : ktn * 32 + lr;
      const int jn1 = (ktn * 32 + 16 + lr > NTOK - 1) ? NTOK - 1 : ktn * 32 + 16 + lr;
      float pb0 = br0[jn0], pb1 = br1[jn0], pb2 = br2[jn0], pb3 = br3[jn0];
      float pb4 = br0[jn1], pb5 = br1[jn1], pb6 = br2[jn1], pb7 = br3[jn1];

      const int j0 = kt * 32 + lr;
      const bool v0 = (j0 < NTOK), v1 = (j0 + 16 < NTOK);

      bf16* buf = &Ps[wave][kt & 1][0];
      {
        float e0 = v0 ? __expf(s0[0] + cb0) : 0.f;
        float e1 = v1 ? __expf(s1[0] + cb4) : 0.f;
        l0 += e0 + e1;
        buf[(lg * 4 + 0) * 40 + lr]      = (bf16)e0;
        buf[(lg * 4 + 0) * 40 + 16 + lr] = (bf16)e1;
      }
      {
        float e0 = v0 ? __expf(s0[1] + cb1) : 0.f;
        float e1 = v1 ? __expf(s1[1] + cb5) : 0.f;
        l1 += e0 + e1;
        buf[(lg * 4 + 1) * 40 + lr]      = (bf16)e0;
        buf[(lg * 4 + 1) * 40 + 16 + lr] = (bf16)e1;
      }
      {
        float e0 = v0 ? __expf(s0[2] + cb2) : 0.f;
        float e1 = v1 ? __expf(s1[2] + cb6) : 0.f;
        l2 += e0 + e1;
        buf[(lg * 4 + 2) * 40 + lr]      = (bf16)e0;
        buf[(lg * 4 + 2) * 40 + 16 + lr] = (bf16)e1;
      }
      {
        float e0 = v0 ? __expf(s0[3] + cb3) : 0.f;
        float e1 = v1 ? __expf(s1[3] + cb7) : 0.f;
        l3 += e0 + e1;
        buf[(lg * 4 + 3) * 40 + lr]      = (bf16)e0;
        buf[(lg * 4 + 3) * 40 + 16 + lr] = (bf16)e1;
      }
      asm volatile("s_waitcnt lgkmcnt(0)" ::: "memory");
      __builtin_amdgcn_sched_barrier(0);
      bf16x8 pa = *(const bf16x8*)&buf[lr * 40 + lg * 8];
#pragma unroll
      for (int nd = 0; nd < 4; ++nd) {
        bf16x8 bv = *(const bf16x8*)&Vt[(nd * 16 + lr) * VTS + kt * 32 + lg * 8];
        oacc[nd] = __builtin_amdgcn_mfma_f32_16x16x32_bf16(pa, bv, oacc[nd], 0, 0, 0);
      }
      ka0 = na0; ka1 = na1; kb0 = nb0; kb1 = nb1;
      cb0 = pb0; cb1 = pb1; cb2 = pb2; cb3 = pb3;
      cb4 = pb4; cb5 = pb5; cb6 = pb6; cb7 = pb7;
    }

    float rowinv[4];
    {
      float ls[4] = {l0, l1, l2, l3};
#pragma unroll
      for (int r = 0; r < 4; ++r) {
        float v = ls[r];
#pragma unroll
        for (int d = 1; d < 16; d <<= 1) v += __shfl_xor(v, d);
        rowinv[r] = 1.0f / v;
      }
    }

    bf16* Ob = &Ps[wave][0][0];   // 16*72*2 = 2304B <= 2560B wave region
#pragma unroll
    for (int nd = 0; nd < 4; ++nd)
#pragma unroll
      for (int r = 0; r < 4; ++r)
        Ob[(lg * 4 + r) * 72 + nd * 16 + lr] = (bf16)(oacc[nd][r] * rowinv[r]);
    asm volatile("s_waitcnt lgkmcnt(0)" ::: "memory");
    __builtin_amdgcn_sched_barrier(0);
    const int rows = NTOK - mi * 16;
#pragma unroll
    for (int pass = 0; pass < 2; ++pass) {
      int orow = pass * 8 + (lane >> 3);
      if (orow < rows) {
        bf16x8 v = *(const bf16x8*)&Ob[orow * 72 + (lane & 7) * 8];
        *(bf16x8*)(out + (size_t)(b * NTOK + mi * 16 + orow) * DIM + h * 64 + (lane & 7) * 8) = v;
      }
    }
  }
}

// ---------------- launch ----------------
extern "C" void kernel_launch(void* const* d_in, const int* in_sizes, int n_in,
                              void* d_out, int out_size, void* d_ws, size_t ws_size,
                              hipStream_t stream) {
  const float* x    = (const float*)d_in[0];
  const float* n1w  = (const float*)d_in[1];
  const float* n1b  = (const float*)d_in[2];
  const float* qkvw = (const float*)d_in[3];
  const float* qb   = (const float*)d_in[4];
  const float* vb   = (const float*)d_in[5];
  const float* pw   = (const float*)d_in[6];
  const float* pb   = (const float*)d_in[7];
  const float* rh   = (const float*)d_in[8];
  const float* rw   = (const float*)d_in[9];
  const float* n2w  = (const float*)d_in[10];
  const float* n2b  = (const float*)d_in[11];
  const float* f1w  = (const float*)d_in[12];
  const float* f1b  = (const float*)d_in[13];
  const float* f2w  = (const float*)d_in[14];
  const float* f2b  = (const float*)d_in[15];
  const int* hidx   = (const int*)d_in[16];
  const int* widx   = (const int*)d_in[17];

  char* ws = (char*)d_ws;
  size_t off = 0;
  auto alloc = [&](size_t bytes) {
    void* p = ws + off;
    off += (bytes + 255) & ~(size_t)255;
    return p;
  };
  bf16* wqkv  = (bf16*)alloc((size_t)2304 * 768 * 2);
  bf16* wproj = (bf16*)alloc((size_t)768 * 768 * 2);
  bf16* wfc1  = (bf16*)alloc((size_t)3072 * 768 * 2);
  bf16* wfc2  = (bf16*)alloc((size_t)768 * 3072 * 2);
  float* biasT = (float*)alloc((size_t)HEADS * NTOK * NTOK * 4);
  bf16* hbf = (bf16*)alloc((size_t)MROWS * 768 * 2);
  bf16* x1  = (bf16*)alloc((size_t)MROWS * 768 * 2);     // bf16 residual intermediate
  char* region = (char*)alloc((size_t)MPAD * HIDN * 2);
  bf16* qkv   = (bf16*)region;                                       // 58.1 MB
  bf16* attno = (bf16*)(region + (size_t)2304 * NTOK * 64 * 2);      // 19.4 MB
  bf16* mbuf  = (bf16*)region;                                       // FC1 out overlays qkv+attno

  const int c0 = 2304 * 768 / 4, c1 = 768 * 768 / 4, c2 = 3072 * 768 / 4, c3 = 768 * 3072 / 4;
  conv4_kernel<<<(c0 + c1 + c2 + c3 + 255) / 256, 256, 0, stream>>>(
      qkvw, wqkv, c0, pw, wproj, c1, f1w, wfc1, c2, f2w, wfc2, c3);
  bias_kernel<<<(HEADS * NTOK * NTOK + 255) / 256, 256, 0, stream>>>(rh, rw, hidx, widx, biasT);

  const int MT = MPAD / 128;  // 99
  ln_kernel<float><<<MROWS, 256, 0, stream>>>(x, n1w, n1b, hbf);
  gemm128<0, 128><<<MT * 18, 256, 0, stream>>>(hbf, wqkv, 768, 2304, 18, qb, vb, qkv);
  attn_kernel<<<1536, 512, 0, stream>>>(qkv, biasT, attno);
  gemm128<3, 64><<<MT * 12, 256, 0, stream>>>(attno, wproj, 768, 768, 12, pb, x, x1);
  ln_kernel<bf16><<<MROWS, 256, 0, stream>>>(x1, n2w, n2b, hbf);
  gemm128<2, 128><<<MT * 24, 256, 0, stream>>>(hbf, wfc1, 768, HIDN, 24, f1b, nullptr, mbuf);
  gemm128<4, 64><<<MT * 12, 256, 0, stream>>>(mbuf, wfc2, HIDN, 768, 12, f2b,
                                              (const float*)(const void*)x1, d_out);
}